// Round 13
// baseline (125.390 us; speedup 1.0000x reference)
//
#include <hip/hip_runtime.h>
#include <cstdint>
#include <cstddef>

#define WD  50
#define MT  256
#define BSZ 4096
#define NCH 8                  // batch chunks per (m,branch): 2048 blocks
#define BCH (BSZ / NCH)        // 512 rows per block
#define ITERS (BCH / 4 / 16)   // 8 iters: per wave 128 rows, 16/iter

typedef __bf16 bf16x8 __attribute__((ext_vector_type(8)));
typedef float  f32x4  __attribute__((ext_vector_type(4)));

#define LOG2E 1.44269504088896340736f

__device__ __forceinline__ float swishf(float x) {
    // x * sigmoid(x) = x * rcp(1 + 2^(-x*log2e)); 5 instrs (2 trans)
    return x * __builtin_amdgcn_rcpf(1.0f + __builtin_amdgcn_exp2f(-LOG2E * x));
}

__device__ __forceinline__ unsigned short bfbits(float x) {
    union { __bf16 b; unsigned short s; } c; c.b = (__bf16)x; return c.s;
}

// Fused 1->50->50->1 MLP, layer-2 on bf16 MFMA (16x16x32), one branch.
// TRANSPOSED orientation: mfma(A=W2, B=h1), D col=batch=l&15,
// row v=vt*16+(l>>4)*4+g [m89]; 2-step lg reduce; b2 as MFMA C-in.
// ROUND-13: total-register diet to lift the ~3 waves/SIMD residency cap
// (r8-r12: VALUBusy pinned ~51%, occupancy ~30% under every scheduling
// change -> register-capped residency is the standing theory).
//   - no pipeline rotation (r12 null)
//   - b2 packed to bf16 pairs: 16 f32 regs -> 8 u32, bit-unpacked at C-init
//   - __launch_bounds__(256,6): total-reg budget 85 (est. need ~76).
//     r7 lesson: (256,8) = budget 64 -> spill disaster; watch FETCH_SIZE.
// MODE 0: out[m*BSZ + b]   MODE 1: out[(b*MT+m)*2+br]   MODE 2: out[b*MT+m]
template<int MODE>
__global__ __launch_bounds__(256, 6) void rmat_mlp_mfma(
    const float* __restrict__ U,
    const float* __restrict__ W1, const float* __restrict__ B1,
    const float* __restrict__ W2, const float* __restrict__ B2,
    const float* __restrict__ W3, const float* __restrict__ B3,
    float* __restrict__ out, int br)
{
    const int m  = blockIdx.x >> 3;        // 0..255
    const int ch = blockIdx.x & 7;         // 0..7

    const float* __restrict__ w1 = W1 + m * WD;
    const float* __restrict__ b1 = B1 + m * WD;
    const float* __restrict__ w2 = W2 + (size_t)m * WD * WD;
    const float* __restrict__ b2 = B2 + m * WD;
    const float* __restrict__ w3 = W3 + m * WD;
    const float  b3v = B3[m];

    const int lane = threadIdx.x & 63;
    const int wid  = threadIdx.x >> 6;
    const int lr   = lane & 15;            // A-row (v mod 16) / D-col (batch)
    const int lg   = lane >> 4;            // k sub-slot / D-row group

    // ---- static per-lane state (one-time prologue) ----
    // logical k for slot (half, lg, e) = half*32 + e*4 + lg  (bijection)
    bf16x8 wfrag[4][2];                    // A-operand: W2, 4 v-tiles x 2 k-halves
#pragma unroll
    for (int vt = 0; vt < 4; ++vt) {
        const int v = vt * 16 + lr;
#pragma unroll
        for (int kt = 0; kt < 2; ++kt)
#pragma unroll
            for (int e = 0; e < 8; ++e) {
                const int k = kt * 32 + e * 4 + lg;
                const float w = (v < WD && k < WD) ? w2[v * WD + k] : 0.0f;
                wfrag[vt][kt][e] = (__bf16)w;
            }
    }
    // layer-1 weights: half0 slots e=0..7 (k=e*4+lg, all <32), half1 e=0..4
    float w1v[13], b1v[13];
#pragma unroll
    for (int e = 0; e < 8; ++e) {
        const int k = e * 4 + lg;
        w1v[e] = w1[k];  b1v[e] = b1[k];
    }
#pragma unroll
    for (int e = 0; e < 5; ++e) {
        const int k = 32 + e * 4 + lg;
        w1v[8 + e] = (k < WD) ? w1[k] : 0.0f;
        b1v[8 + e] = (k < WD) ? b1[k] : 0.0f;
    }
    // layer-3: v = vt*16 + lg*4 + g per (vt,g); b2 packed bf16x2 (8 regs)
    unsigned b2p[4][2];
    float w3v[4][4];
#pragma unroll
    for (int vt = 0; vt < 4; ++vt) {
#pragma unroll
        for (int g = 0; g < 4; ++g) {
            const int v = vt * 16 + lg * 4 + g;
            w3v[vt][g] = (v < WD) ? w3[v] : 0.0f;
        }
#pragma unroll
        for (int h = 0; h < 2; ++h) {
            const int v0 = vt * 16 + lg * 4 + 2 * h;
            const float f0 = (v0 < WD) ? b2[v0] : 0.0f;
            const float f1 = (v0 + 1 < WD) ? b2[v0 + 1] : 0.0f;
            b2p[vt][h] = (unsigned)bfbits(f0) | ((unsigned)bfbits(f1) << 16);
        }
    }

    float* __restrict__ dst = out + (size_t)m * BSZ;   // MODE 0 base
    const int b0 = ch * BCH + wid * (BCH / 4);         // wave's 128-row slice

#pragma unroll 1
    for (int it = 0; it < ITERS; ++it) {
        const int bb = b0 + it * 16;
        const float u = U[bb + lr];

        // layer 1 -> B fragments (batch col = lr); pad slots constant 0
        bf16x8 a0, a1 = {};
#pragma unroll
        for (int e = 0; e < 8; ++e)
            a0[e] = (__bf16)swishf(fmaf(u, w1v[e], b1v[e]));
#pragma unroll
        for (int e = 0; e < 5; ++e)
            a1[e] = (__bf16)swishf(fmaf(u, w1v[8 + e], b1v[8 + e]));

        // layer 2: D[v][batch]; b2 unpacked from bf16 pairs into C-in
        f32x4 acc[4];
#pragma unroll
        for (int vt = 0; vt < 4; ++vt) {
            const unsigned p0 = b2p[vt][0], p1 = b2p[vt][1];
            acc[vt][0] = __uint_as_float(p0 << 16);
            acc[vt][1] = __uint_as_float(p0 & 0xffff0000u);
            acc[vt][2] = __uint_as_float(p1 << 16);
            acc[vt][3] = __uint_as_float(p1 & 0xffff0000u);
            acc[vt] = __builtin_amdgcn_mfma_f32_16x16x32_bf16(wfrag[vt][0], a0, acc[vt], 0, 0, 0);
            acc[vt] = __builtin_amdgcn_mfma_f32_16x16x32_bf16(wfrag[vt][1], a1, acc[vt], 0, 0, 0);
        }

        // layer 3: 16 in-lane swish+dot, then 2-step reduce over lg lanes
        float p0 = 0.0f, p1 = 0.0f, p2 = 0.0f, p3 = 0.0f;
#pragma unroll
        for (int g = 0; g < 4; ++g) {
            p0 = fmaf(w3v[0][g], swishf(acc[0][g]), p0);
            p1 = fmaf(w3v[1][g], swishf(acc[1][g]), p1);
            p2 = fmaf(w3v[2][g], swishf(acc[2][g]), p2);
            p3 = fmaf(w3v[3][g], swishf(acc[3][g]), p3);
        }
        float p = (p0 + p1) + (p2 + p3);
        p += __shfl_xor(p, 16);
        p += __shfl_xor(p, 32);

        if (lane < 16) {                    // lg==0: one result per batch col
            const int row = bb + lane;
            if (MODE == 0)      dst[row] = p + b3v;            // 64B/wave, coalesced
            else if (MODE == 1) out[((size_t)row * MT + m) * 2 + br] = p + b3v;
            else                out[(size_t)row * MT + m] = p + b3v;
        }
    }
}

// ws[NBR][256][4096] -> out. NBR=2: [b][m][re,im]; NBR=1: transpose to [b][m].
// (Verbatim from the round-2/5/6 PASS.)
template<int NBR>
__global__ __launch_bounds__(256) void rmat_interleave(
    const float* __restrict__ ws, float* __restrict__ out)
{
    __shared__ float tile[NBR][32][64 + 1];
    const int bt = blockIdx.x & 63;
    const int mt = blockIdx.x >> 6;
    const int b0 = bt * 64, m0 = mt * 32;

    for (int i = threadIdx.x; i < NBR * 32 * 64; i += 256) {
        const int brx = i >> 11;           // 0 when NBR==1
        const int r   = (i >> 6) & 31;
        const int c   = i & 63;
        tile[brx][r][c] = ws[(size_t)(brx * MT + m0 + r) * BSZ + b0 + c];
    }
    __syncthreads();

    const int tb   = threadIdx.x >> 2;
    const int part = threadIdx.x & 3;
    const int b = b0 + tb;
    if (NBR == 2) {
        float2* __restrict__ dstp =
            reinterpret_cast<float2*>(out) + (size_t)b * MT + m0 + part * 8;
#pragma unroll
        for (int k = 0; k < 8; ++k) {
            const int mm = part * 8 + k;
            dstp[k] = make_float2(tile[0][mm][tb], tile[1][mm][tb]);
        }
    } else {
        float* __restrict__ dstp = out + (size_t)b * MT + m0 + part * 8;
#pragma unroll
        for (int k = 0; k < 8; ++k)
            dstp[k] = tile[0][part * 8 + k][tb];
    }
}

extern "C" void kernel_launch(void* const* d_in, const int* in_sizes, int n_in,
                              void* d_out, int out_size, void* d_ws, size_t ws_size,
                              hipStream_t stream) {
    const float* U   = (const float*)d_in[0];
    const float* W1r = (const float*)d_in[1];
    const float* b1r = (const float*)d_in[2];
    const float* W2r = (const float*)d_in[3];
    const float* b2r = (const float*)d_in[4];
    const float* W3r = (const float*)d_in[5];
    const float* b3r = (const float*)d_in[6];
    const float* W1i = (const float*)d_in[7];
    const float* b1i = (const float*)d_in[8];
    const float* W2i = (const float*)d_in[9];
    const float* b2i = (const float*)d_in[10];
    const float* W3i = (const float*)d_in[11];
    const float* b3i = (const float*)d_in[12];
    float* out = (float*)d_out;
    float* ws  = (float*)d_ws;

    const dim3 grid(MT * NCH), block(256);
    const size_t plane = (size_t)MT * BSZ;   // floats per branch

    if (out_size >= (int)(2 * plane)) {
        // d_out = [B][M] of (re,im) float pairs
        if (ws_size >= 2 * plane * sizeof(float)) {
            rmat_mlp_mfma<0><<<grid, block, 0, stream>>>(U, W1r, b1r, W2r, b2r, W3r, b3r, ws, 0);
            rmat_mlp_mfma<0><<<grid, block, 0, stream>>>(U, W1i, b1i, W2i, b2i, W3i, b3i, ws + plane, 1);
            rmat_interleave<2><<<dim3(512), block, 0, stream>>>(ws, out);
        } else {
            rmat_mlp_mfma<1><<<grid, block, 0, stream>>>(U, W1r, b1r, W2r, b2r, W3r, b3r, out, 0);
            rmat_mlp_mfma<1><<<grid, block, 0, stream>>>(U, W1i, b1i, W2i, b2i, W3i, b3i, out, 1);
        }
    } else {
        // d_out holds B*M float32 -> real branch only (harness drops imag)
        if (ws_size >= plane * sizeof(float)) {
            rmat_mlp_mfma<0><<<grid, block, 0, stream>>>(U, W1r, b1r, W2r, b2r, W3r, b3r, ws, 0);
            rmat_interleave<1><<<dim3(512), block, 0, stream>>>(ws, out);
        } else {
            rmat_mlp_mfma<2><<<grid, block, 0, stream>>>(U, W1r, b1r, W2r, b2r, W3r, b3r, out, 0);
        }
    }
}

// Round 14
// 67.778 us; speedup vs baseline: 1.8500x; 1.8500x over previous
//
#include <hip/hip_runtime.h>
#include <cstdint>
#include <cstddef>

#define WD  50
#define MT  256
#define BSZ 4096
#define NCH 8                  // batch chunks per (m,branch): 2048 blocks
#define BCH (BSZ / NCH)        // 512 rows per block
#define ITERS (BCH / 4 / 16)   // 8 iters: per wave 128 rows, 16/iter

typedef __bf16 bf16x8 __attribute__((ext_vector_type(8)));
typedef float  f32x4  __attribute__((ext_vector_type(4)));

#define LOG2E 1.44269504088896340736f

__device__ __forceinline__ float swishf(float x) {
    // x * sigmoid(x) = x * rcp(1 + 2^(-x*log2e)); 5 instrs (2 trans)
    return x * __builtin_amdgcn_rcpf(1.0f + __builtin_amdgcn_exp2f(-LOG2E * x));
}

__device__ __forceinline__ unsigned short bfbits(float x) {
    union { __bf16 b; unsigned short s; } c; c.b = (__bf16)x; return c.s;
}
__device__ __forceinline__ float bfhi(unsigned u)  { return __uint_as_float(u & 0xffff0000u); }
__device__ __forceinline__ float bflo(unsigned u)  { return __uint_as_float(u << 16); }

// Fused 1->50->50->1 MLP, layer-2 on bf16 MFMA (16x16x32), one branch.
// TRANSPOSED orientation: mfma(A=W2, B=h1), D col=batch=l&15,
// row v=vt*16+(l>>4)*4+g [m89]; 2-step lg reduce; b2/w3 bf16-packed.
// ROUND-14: W2 moved to LDS (loop-invariant 32-reg block -> 8 ds_read_b128
// per iter, streamed per-vt) to ACTUALLY shrink the per-wave register
// footprint, then __launch_bounds__(256,5) (budget 102, est. need ~90).
// r13 proved occupancy is register-capped (52% at 6 waves) but an
// under-budget cap spills; this time the state is genuinely smaller.
// LDS slot layout: lds[v][s], s-chunk c=s>>3 = kt*4+lg holds k=kt*32+e*4+lg
// (r13's exact k-map -> MFMA slot contents bit-identical), XOR-swizzled
// s ^= (v&7)<<3 so 16B fragment reads spread across banks (G4).
// MODE 0: out[m*BSZ + b]   MODE 1: out[(b*MT+m)*2+br]   MODE 2: out[b*MT+m]
template<int MODE>
__global__ __launch_bounds__(256, 5) void rmat_mlp_mfma(
    const float* __restrict__ U,
    const float* __restrict__ W1, const float* __restrict__ B1,
    const float* __restrict__ W2, const float* __restrict__ B2,
    const float* __restrict__ W3, const float* __restrict__ B3,
    float* __restrict__ out, int br)
{
    __shared__ __bf16 w2s[64 * 64];        // 8 KB

    const int m  = blockIdx.x >> 3;        // 0..255
    const int ch = blockIdx.x & 7;         // 0..7

    const float* __restrict__ w1 = W1 + m * WD;
    const float* __restrict__ b1 = B1 + m * WD;
    const float* __restrict__ w2 = W2 + (size_t)m * WD * WD;
    const float* __restrict__ b2 = B2 + m * WD;
    const float* __restrict__ w3 = W3 + m * WD;
    const float  b3v = B3[m];

    const int lane = threadIdx.x & 63;
    const int wid  = threadIdx.x >> 6;
    const int lr   = lane & 15;            // A-row (v mod 16) / D-col (batch)
    const int lg   = lane >> 4;            // k sub-slot / D-row group

    // ---- stage W2 -> LDS (slot-permuted + XOR-swizzled), once ----
    for (int idx = threadIdx.x; idx < 64 * 64; idx += 256) {
        const int v  = idx >> 6;
        const int s  = idx & 63;
        const int kk = ((s >> 5) << 5) + ((s & 7) << 2) + ((s >> 3) & 3);
        const float w = (v < WD && kk < WD) ? w2[v * WD + kk] : 0.0f;
        w2s[(v << 6) + (s ^ ((v & 7) << 3))] = (__bf16)w;
    }

    // layer-1 weights: k = half*32 + e*4 + lg; half1 e>=5 is all-pad
    float w1v[13], b1v[13];
#pragma unroll
    for (int e = 0; e < 8; ++e) {
        const int k = e * 4 + lg;
        w1v[e] = w1[k];  b1v[e] = b1[k];
    }
#pragma unroll
    for (int e = 0; e < 5; ++e) {
        const int k = 32 + e * 4 + lg;
        w1v[8 + e] = (k < WD) ? w1[k] : 0.0f;
        b1v[8 + e] = (k < WD) ? b1[k] : 0.0f;
    }
    // layer-3 constants, bf16-packed pairs: v = vt*16 + lg*4 + g
    unsigned b2p[4][2], w3p[4][2];
#pragma unroll
    for (int vt = 0; vt < 4; ++vt)
#pragma unroll
        for (int h = 0; h < 2; ++h) {
            const int v0 = vt * 16 + lg * 4 + 2 * h;
            const float f0 = (v0 < WD) ? b2[v0] : 0.0f;
            const float f1 = (v0 + 1 < WD) ? b2[v0 + 1] : 0.0f;
            b2p[vt][h] = (unsigned)bfbits(f0) | ((unsigned)bfbits(f1) << 16);
            const float g0 = (v0 < WD) ? w3[v0] : 0.0f;
            const float g1 = (v0 + 1 < WD) ? w3[v0 + 1] : 0.0f;
            w3p[vt][h] = (unsigned)bfbits(g0) | ((unsigned)bfbits(g1) << 16);
        }

    __syncthreads();

    float* __restrict__ dst = out + (size_t)m * BSZ;   // MODE 0 base
    const int b0 = ch * BCH + wid * (BCH / 4);         // wave's 128-row slice

#pragma unroll 1
    for (int it = 0; it < ITERS; ++it) {
        const int bb = b0 + it * 16;
        const float u = U[bb + lr];

        // layer 1 -> B fragments (batch col = lr); pad slots constant 0
        bf16x8 a0, a1 = {};
#pragma unroll
        for (int e = 0; e < 8; ++e)
            a0[e] = (__bf16)swishf(fmaf(u, w1v[e], b1v[e]));
#pragma unroll
        for (int e = 0; e < 5; ++e)
            a1[e] = (__bf16)swishf(fmaf(u, w1v[8 + e], b1v[8 + e]));

        // layer 2: per-vt {2 ds_read_b128, 2 MFMA}; b2 unpacked into C-in
        f32x4 acc[4];
#pragma unroll
        for (int vt = 0; vt < 4; ++vt) {
            const int v    = vt * 16 + lr;
            const int base = (v << 6);
            const int sw   = (v & 7) << 3;
            const bf16x8 f0 = *reinterpret_cast<const bf16x8*>(
                &w2s[base + ((lg << 3) ^ sw)]);            // kt=0, chunk lg
            const bf16x8 f1 = *reinterpret_cast<const bf16x8*>(
                &w2s[base + (((4 + lg) << 3) ^ sw)]);      // kt=1, chunk 4+lg
            acc[vt][0] = bflo(b2p[vt][0]);
            acc[vt][1] = bfhi(b2p[vt][0]);
            acc[vt][2] = bflo(b2p[vt][1]);
            acc[vt][3] = bfhi(b2p[vt][1]);
            acc[vt] = __builtin_amdgcn_mfma_f32_16x16x32_bf16(f0, a0, acc[vt], 0, 0, 0);
            acc[vt] = __builtin_amdgcn_mfma_f32_16x16x32_bf16(f1, a1, acc[vt], 0, 0, 0);
        }

        // layer 3: 16 in-lane swish+dot (w3 unpacked inline), 2-step reduce
        float p0 = 0.0f, p1 = 0.0f, p2 = 0.0f, p3 = 0.0f;
#pragma unroll
        for (int g = 0; g < 4; ++g) {
            const float wa = (g & 1) ? bfhi(w3p[0][g >> 1]) : bflo(w3p[0][g >> 1]);
            const float wb = (g & 1) ? bfhi(w3p[1][g >> 1]) : bflo(w3p[1][g >> 1]);
            const float wc = (g & 1) ? bfhi(w3p[2][g >> 1]) : bflo(w3p[2][g >> 1]);
            const float wd = (g & 1) ? bfhi(w3p[3][g >> 1]) : bflo(w3p[3][g >> 1]);
            p0 = fmaf(wa, swishf(acc[0][g]), p0);
            p1 = fmaf(wb, swishf(acc[1][g]), p1);
            p2 = fmaf(wc, swishf(acc[2][g]), p2);
            p3 = fmaf(wd, swishf(acc[3][g]), p3);
        }
        float p = (p0 + p1) + (p2 + p3);
        p += __shfl_xor(p, 16);
        p += __shfl_xor(p, 32);

        if (lane < 16) {                    // lg==0: one result per batch col
            const int row = bb + lane;
            if (MODE == 0)      dst[row] = p + b3v;            // 64B/wave, coalesced
            else if (MODE == 1) out[((size_t)row * MT + m) * 2 + br] = p + b3v;
            else                out[(size_t)row * MT + m] = p + b3v;
        }
    }
}

// ws[NBR][256][4096] -> out. NBR=2: [b][m][re,im]; NBR=1: transpose to [b][m].
// (Verbatim from the round-2/5/6 PASS.)
template<int NBR>
__global__ __launch_bounds__(256) void rmat_interleave(
    const float* __restrict__ ws, float* __restrict__ out)
{
    __shared__ float tile[NBR][32][64 + 1];
    const int bt = blockIdx.x & 63;
    const int mt = blockIdx.x >> 6;
    const int b0 = bt * 64, m0 = mt * 32;

    for (int i = threadIdx.x; i < NBR * 32 * 64; i += 256) {
        const int brx = i >> 11;           // 0 when NBR==1
        const int r   = (i >> 6) & 31;
        const int c   = i & 63;
        tile[brx][r][c] = ws[(size_t)(brx * MT + m0 + r) * BSZ + b0 + c];
    }
    __syncthreads();

    const int tb   = threadIdx.x >> 2;
    const int part = threadIdx.x & 3;
    const int b = b0 + tb;
    if (NBR == 2) {
        float2* __restrict__ dstp =
            reinterpret_cast<float2*>(out) + (size_t)b * MT + m0 + part * 8;
#pragma unroll
        for (int k = 0; k < 8; ++k) {
            const int mm = part * 8 + k;
            dstp[k] = make_float2(tile[0][mm][tb], tile[1][mm][tb]);
        }
    } else {
        float* __restrict__ dstp = out + (size_t)b * MT + m0 + part * 8;
#pragma unroll
        for (int k = 0; k < 8; ++k)
            dstp[k] = tile[0][part * 8 + k][tb];
    }
}

extern "C" void kernel_launch(void* const* d_in, const int* in_sizes, int n_in,
                              void* d_out, int out_size, void* d_ws, size_t ws_size,
                              hipStream_t stream) {
    const float* U   = (const float*)d_in[0];
    const float* W1r = (const float*)d_in[1];
    const float* b1r = (const float*)d_in[2];
    const float* W2r = (const float*)d_in[3];
    const float* b2r = (const float*)d_in[4];
    const float* W3r = (const float*)d_in[5];
    const float* b3r = (const float*)d_in[6];
    const float* W1i = (const float*)d_in[7];
    const float* b1i = (const float*)d_in[8];
    const float* W2i = (const float*)d_in[9];
    const float* b2i = (const float*)d_in[10];
    const float* W3i = (const float*)d_in[11];
    const float* b3i = (const float*)d_in[12];
    float* out = (float*)d_out;
    float* ws  = (float*)d_ws;

    const dim3 grid(MT * NCH), block(256);
    const size_t plane = (size_t)MT * BSZ;   // floats per branch

    if (out_size >= (int)(2 * plane)) {
        // d_out = [B][M] of (re,im) float pairs
        if (ws_size >= 2 * plane * sizeof(float)) {
            rmat_mlp_mfma<0><<<grid, block, 0, stream>>>(U, W1r, b1r, W2r, b2r, W3r, b3r, ws, 0);
            rmat_mlp_mfma<0><<<grid, block, 0, stream>>>(U, W1i, b1i, W2i, b2i, W3i, b3i, ws + plane, 1);
            rmat_interleave<2><<<dim3(512), block, 0, stream>>>(ws, out);
        } else {
            rmat_mlp_mfma<1><<<grid, block, 0, stream>>>(U, W1r, b1r, W2r, b2r, W3r, b3r, out, 0);
            rmat_mlp_mfma<1><<<grid, block, 0, stream>>>(U, W1i, b1i, W2i, b2i, W3i, b3i, out, 1);
        }
    } else {
        // d_out holds B*M float32 -> real branch only (harness drops imag)
        if (ws_size >= plane * sizeof(float)) {
            rmat_mlp_mfma<0><<<grid, block, 0, stream>>>(U, W1r, b1r, W2r, b2r, W3r, b3r, ws, 0);
            rmat_interleave<1><<<dim3(512), block, 0, stream>>>(ws, out);
        } else {
            rmat_mlp_mfma<2><<<grid, block, 0, stream>>>(U, W1r, b1r, W2r, b2r, W3r, b3r, out, 0);
        }
    }
}

// Round 15
// 49.640 us; speedup vs baseline: 2.5260x; 1.3654x over previous
//
#include <hip/hip_runtime.h>
#include <cstdint>
#include <cstddef>

#define WD  50
#define MT  256
#define BSZ 4096
#define NCH 16                 // batch chunks: 4096 one-wave blocks
#define BCH (BSZ / NCH)        // 256 rows per block (= per wave)
#define ITERS (BCH / 16)       // 16 iters, 16 rows each

typedef __bf16 bf16x8 __attribute__((ext_vector_type(8)));
typedef float  f32x4  __attribute__((ext_vector_type(4)));

#define LOG2E 1.44269504088896340736f

__device__ __forceinline__ float swishf(float x) {
    // x * sigmoid(x) = x * rcp(1 + 2^(-x*log2e)); 5 instrs (2 trans)
    return x * __builtin_amdgcn_rcpf(1.0f + __builtin_amdgcn_exp2f(-LOG2E * x));
}

// Fused 1->50->50->1 MLP, layer-2 on bf16 MFMA (16x16x32), one branch.
// ROUND-15 structure:
//  * ONE WAVE PER BLOCK (64 threads, 4096 blocks): same 4 waves/SIMD
//    residency as r10, but the waves sharing a SIMD come from independent
//    blocks -> their trans/MFMA/shfl stall phases decorrelate (r10-r12:
//    lockstep waves of one block pinned VALUBusy at ~51%).
//  * k-slot map (r10): k = kt*32 + e*4 + lg; layer-1 pad uniform -> 13 swishes.
//  * v-slot map (new): v = s*4 + lg, s = vt*4 + g; A-rows permuted to match
//    (vrow(lr) = vt*16 + (lr&3)*4 + (lr>>2)) -> pad slots s=13..15 are
//    wave-uniform -> layer-3 swishes 16 -> 13.
//  * D layout [m89]: row r = lg*4+g -> v = vt*16+(r&3)*4+(r>>2) = s*4+lg.
// r7/r13/r14 lesson: never budget-squeeze registers; (64,4) = 128-reg cap.
// MODE 0: out[m*BSZ + b]   MODE 1: out[(b*MT+m)*2+br]   MODE 2: out[b*MT+m]
template<int MODE>
__global__ __launch_bounds__(64, 4) void rmat_mlp_mfma(
    const float* __restrict__ U,
    const float* __restrict__ W1, const float* __restrict__ B1,
    const float* __restrict__ W2, const float* __restrict__ B2,
    const float* __restrict__ W3, const float* __restrict__ B3,
    float* __restrict__ out, int br)
{
    const int m  = blockIdx.x >> 4;        // 0..255
    const int ch = blockIdx.x & 15;        // 0..15

    const float* __restrict__ w1 = W1 + m * WD;
    const float* __restrict__ b1 = B1 + m * WD;
    const float* __restrict__ w2 = W2 + (size_t)m * WD * WD;
    const float* __restrict__ b2 = B2 + m * WD;
    const float* __restrict__ w3 = W3 + m * WD;
    const float  b3v = B3[m];

    const int lane = threadIdx.x;          // 0..63
    const int lr   = lane & 15;            // A-row index / D-col (batch)
    const int lg   = lane >> 4;            // k sub-slot / D-row group

    // ---- static per-lane state (one-time prologue) ----
    // A-operand (W2): A-row lr holds W2 row vrow = vt*16 + (lr&3)*4 + (lr>>2)
    // slot (kt,e): k = kt*32 + e*4 + lg
    bf16x8 wfrag[4][2];
    const int vsub = ((lr & 3) << 2) + (lr >> 2);   // (lr&3)*4 + lr/4
#pragma unroll
    for (int vt = 0; vt < 4; ++vt) {
        const int vrow = vt * 16 + vsub;
#pragma unroll
        for (int kt = 0; kt < 2; ++kt)
#pragma unroll
            for (int e = 0; e < 8; ++e) {
                const int k = kt * 32 + e * 4 + lg;
                const float w = (vrow < WD && k < WD) ? w2[vrow * WD + k] : 0.0f;
                wfrag[vt][kt][e] = (__bf16)w;
            }
    }
    // layer-1 weights: k = half*32 + e*4 + lg; half1 e>=5 is all-pad
    float w1v[13], b1v[13];
#pragma unroll
    for (int e = 0; e < 8; ++e) {
        const int k = e * 4 + lg;
        w1v[e] = w1[k];  b1v[e] = b1[k];
    }
#pragma unroll
    for (int e = 0; e < 5; ++e) {
        const int k = 32 + e * 4 + lg;
        w1v[8 + e] = (k < WD) ? w1[k] : 0.0f;
        b1v[8 + e] = (k < WD) ? b1[k] : 0.0f;
    }
    // layer-3 constants: slot s -> v = s*4 + lg. s=13..15 dead (w3=b2=0).
    float b2v[16], w3v[13];
#pragma unroll
    for (int s = 0; s < 16; ++s) {
        const int v = s * 4 + lg;
        b2v[s] = (s < 13 && v < WD) ? b2[v] : 0.0f;
    }
#pragma unroll
    for (int s = 0; s < 13; ++s) {
        const int v = s * 4 + lg;
        w3v[s] = (v < WD) ? w3[v] : 0.0f;
    }

    float* __restrict__ dst = out + (size_t)m * BSZ;   // MODE 0 base
    const int b0 = ch * BCH;               // this wave's 256-row slice

#pragma unroll 1
    for (int it = 0; it < ITERS; ++it) {
        const int bb = b0 + it * 16;
        const float u = U[bb + lr];

        // layer 1 -> B fragments (batch col = lr); pad slots constant 0
        bf16x8 a0, a1 = {};
#pragma unroll
        for (int e = 0; e < 8; ++e)
            a0[e] = (__bf16)swishf(fmaf(u, w1v[e], b1v[e]));
#pragma unroll
        for (int e = 0; e < 5; ++e)
            a1[e] = (__bf16)swishf(fmaf(u, w1v[8 + e], b1v[8 + e]));

        // layer 2: D[v][batch]; b2 enters as C-in
        f32x4 acc[4];
#pragma unroll
        for (int vt = 0; vt < 4; ++vt) {
            acc[vt] = (f32x4){b2v[vt * 4 + 0], b2v[vt * 4 + 1],
                              b2v[vt * 4 + 2], b2v[vt * 4 + 3]};
            acc[vt] = __builtin_amdgcn_mfma_f32_16x16x32_bf16(wfrag[vt][0], a0, acc[vt], 0, 0, 0);
            acc[vt] = __builtin_amdgcn_mfma_f32_16x16x32_bf16(wfrag[vt][1], a1, acc[vt], 0, 0, 0);
        }

        // layer 3: 13 live slots (s=13..15 wave-uniform pad), 4 chains,
        // then 2-step reduce over the 4 lg groups
        float pa = 0.0f, pb = 0.0f, pc = 0.0f, pd = 0.0f;
#pragma unroll
        for (int s = 0; s < 13; ++s) {
            const float y = swishf(acc[s >> 2][s & 3]);
            if ((s & 3) == 0)      pa = fmaf(w3v[s], y, pa);
            else if ((s & 3) == 1) pb = fmaf(w3v[s], y, pb);
            else if ((s & 3) == 2) pc = fmaf(w3v[s], y, pc);
            else                   pd = fmaf(w3v[s], y, pd);
        }
        float p = (pa + pb) + (pc + pd);
        p += __shfl_xor(p, 16);
        p += __shfl_xor(p, 32);

        if (lane < 16) {                    // lg==0: one result per batch col
            const int row = bb + lane;
            if (MODE == 0)      dst[row] = p + b3v;            // 64B/wave, coalesced
            else if (MODE == 1) out[((size_t)row * MT + m) * 2 + br] = p + b3v;
            else                out[(size_t)row * MT + m] = p + b3v;
        }
    }
}

// ws[NBR][256][4096] -> out. NBR=2: [b][m][re,im]; NBR=1: transpose to [b][m].
// (Verbatim from the round-2/5/6 PASS.)
template<int NBR>
__global__ __launch_bounds__(256) void rmat_interleave(
    const float* __restrict__ ws, float* __restrict__ out)
{
    __shared__ float tile[NBR][32][64 + 1];
    const int bt = blockIdx.x & 63;
    const int mt = blockIdx.x >> 6;
    const int b0 = bt * 64, m0 = mt * 32;

    for (int i = threadIdx.x; i < NBR * 32 * 64; i += 256) {
        const int brx = i >> 11;           // 0 when NBR==1
        const int r   = (i >> 6) & 31;
        const int c   = i & 63;
        tile[brx][r][c] = ws[(size_t)(brx * MT + m0 + r) * BSZ + b0 + c];
    }
    __syncthreads();

    const int tb   = threadIdx.x >> 2;
    const int part = threadIdx.x & 3;
    const int b = b0 + tb;
    if (NBR == 2) {
        float2* __restrict__ dstp =
            reinterpret_cast<float2*>(out) + (size_t)b * MT + m0 + part * 8;
#pragma unroll
        for (int k = 0; k < 8; ++k) {
            const int mm = part * 8 + k;
            dstp[k] = make_float2(tile[0][mm][tb], tile[1][mm][tb]);
        }
    } else {
        float* __restrict__ dstp = out + (size_t)b * MT + m0 + part * 8;
#pragma unroll
        for (int k = 0; k < 8; ++k)
            dstp[k] = tile[0][part * 8 + k][tb];
    }
}

extern "C" void kernel_launch(void* const* d_in, const int* in_sizes, int n_in,
                              void* d_out, int out_size, void* d_ws, size_t ws_size,
                              hipStream_t stream) {
    const float* U   = (const float*)d_in[0];
    const float* W1r = (const float*)d_in[1];
    const float* b1r = (const float*)d_in[2];
    const float* W2r = (const float*)d_in[3];
    const float* b2r = (const float*)d_in[4];
    const float* W3r = (const float*)d_in[5];
    const float* b3r = (const float*)d_in[6];
    const float* W1i = (const float*)d_in[7];
    const float* b1i = (const float*)d_in[8];
    const float* W2i = (const float*)d_in[9];
    const float* b2i = (const float*)d_in[10];
    const float* W3i = (const float*)d_in[11];
    const float* b3i = (const float*)d_in[12];
    float* out = (float*)d_out;
    float* ws  = (float*)d_ws;

    const dim3 grid(MT * NCH), block(64);
    const size_t plane = (size_t)MT * BSZ;   // floats per branch

    if (out_size >= (int)(2 * plane)) {
        // d_out = [B][M] of (re,im) float pairs
        if (ws_size >= 2 * plane * sizeof(float)) {
            rmat_mlp_mfma<0><<<grid, block, 0, stream>>>(U, W1r, b1r, W2r, b2r, W3r, b3r, ws, 0);
            rmat_mlp_mfma<0><<<grid, block, 0, stream>>>(U, W1i, b1i, W2i, b2i, W3i, b3i, ws + plane, 1);
            rmat_interleave<2><<<dim3(512), dim3(256), 0, stream>>>(ws, out);
        } else {
            rmat_mlp_mfma<1><<<grid, block, 0, stream>>>(U, W1r, b1r, W2r, b2r, W3r, b3r, out, 0);
            rmat_mlp_mfma<1><<<grid, block, 0, stream>>>(U, W1i, b1i, W2i, b2i, W3i, b3i, out, 1);
        }
    } else {
        // d_out holds B*M float32 -> real branch only (harness drops imag)
        if (ws_size >= plane * sizeof(float)) {
            rmat_mlp_mfma<0><<<grid, block, 0, stream>>>(U, W1r, b1r, W2r, b2r, W3r, b3r, ws, 0);
            rmat_interleave<1><<<dim3(512), dim3(256), 0, stream>>>(ws, out);
        } else {
            rmat_mlp_mfma<2><<<grid, block, 0, stream>>>(U, W1r, b1r, W2r, b2r, W3r, b3r, out, 0);
        }
    }
}

// Round 16
// 42.219 us; speedup vs baseline: 2.9700x; 1.1758x over previous
//
#include <hip/hip_runtime.h>
#include <cstdint>
#include <cstddef>

#define WD  50
#define MT  256
#define BSZ 4096
#define NCH 4                  // batch chunks: 1024 blocks of 4 waves
#define BCH (BSZ / NCH)        // 1024 rows per block
#define ITERS (BCH / 4 / 16)   // 16 iters per wave, 16 rows each

typedef __bf16 bf16x8 __attribute__((ext_vector_type(8)));
typedef float  f32x4  __attribute__((ext_vector_type(4)));

#define LOG2E 1.44269504088896340736f

__device__ __forceinline__ float swishf(float x) {
    // x * sigmoid(x) = x * rcp(1 + 2^(-x*log2e)); 5 instrs (2 trans)
    return x * __builtin_amdgcn_rcpf(1.0f + __builtin_amdgcn_exp2f(-LOG2E * x));
}

// Fused 1->50->50->1 MLP, layer-2 on bf16 MFMA (16x16x32), one branch.
// ROUND-16: same loop as r15 (k-map kt*32+e*4+lg, v-map s*4+lg with
// permuted A-rows, 13+13 swishes, b2 as C-in, 2-shfl reduce) but the
// per-wave prologue's 64 SCATTERED global loads for wfrag are replaced by
// coalesced staging of W2 into LDS (permuted + XOR-swizzled) and
// 8 ds_read_b128 per lane. Theory: r6->r8 showed ~5K cycles per extra
// wave-prologue (scatter-bound); prologue ~= 8 us of the 48 us kernel,
// and its fixity explains why all loop-level changes (r8-r15) were null.
// Registers: loop state unchanged (~64 VGPR, proven no-spill); budget 128.
// MODE 0: out[m*BSZ + b]   MODE 1: out[(b*MT+m)*2+br]   MODE 2: out[b*MT+m]
template<int MODE>
__global__ __launch_bounds__(256, 4) void rmat_mlp_mfma(
    const float* __restrict__ U,
    const float* __restrict__ W1, const float* __restrict__ B1,
    const float* __restrict__ W2, const float* __restrict__ B2,
    const float* __restrict__ W3, const float* __restrict__ B3,
    float* __restrict__ out, int br)
{
    __shared__ __bf16 w2s[64 * 64];        // 8 KB, row = W2 row v, 64 slots

    const int m  = blockIdx.x >> 2;        // 0..255
    const int ch = blockIdx.x & 3;         // 0..3

    const float* __restrict__ w1 = W1 + m * WD;
    const float* __restrict__ b1 = B1 + m * WD;
    const float* __restrict__ w2 = W2 + (size_t)m * WD * WD;
    const float* __restrict__ b2 = B2 + m * WD;
    const float* __restrict__ w3 = W3 + m * WD;
    const float  b3v = B3[m];

    const int lane = threadIdx.x & 63;
    const int wid  = threadIdx.x >> 6;
    const int lr   = lane & 15;            // A-row index / D-col (batch)
    const int lg   = lane >> 4;            // k sub-slot / D-row group

    // ---- stage W2 -> LDS, coalesced reads, permuted+swizzled writes ----
    // slot s = (kt*4+lgg)*8 + e  holds k = kt*32 + e*4 + lgg  (r15 k-map);
    // byte-level XOR swizzle: s ^= (v&7)<<3 (16B granule, G4 bank spread).
    for (int idx = threadIdx.x; idx < 64 * 64; idx += 256) {
        const int v   = idx >> 6;          // W2 row 0..63
        const int s   = idx & 63;
        const int kt  = s >> 5;
        const int lgg = (s >> 3) & 3;
        const int e   = s & 7;
        const int k   = kt * 32 + e * 4 + lgg;
        const float w = (v < WD && k < WD) ? w2[v * WD + k] : 0.0f;
        w2s[(v << 6) + (s ^ ((v & 7) << 3))] = (__bf16)w;
    }

    // layer-1 weights: k = half*32 + e*4 + lg; half1 e>=5 is all-pad
    float w1v[13], b1v[13];
#pragma unroll
    for (int e = 0; e < 8; ++e) {
        const int k = e * 4 + lg;
        w1v[e] = w1[k];  b1v[e] = b1[k];
    }
#pragma unroll
    for (int e = 0; e < 5; ++e) {
        const int k = 32 + e * 4 + lg;
        w1v[8 + e] = (k < WD) ? w1[k] : 0.0f;
        b1v[8 + e] = (k < WD) ? b1[k] : 0.0f;
    }
    // layer-3 constants: slot s -> v = s*4 + lg; s=13..15 dead (w3=b2=0)
    float b2v[16], w3v[13];
#pragma unroll
    for (int s = 0; s < 16; ++s) {
        const int v = s * 4 + lg;
        b2v[s] = (s < 13 && v < WD) ? b2[v] : 0.0f;
    }
#pragma unroll
    for (int s = 0; s < 13; ++s) {
        const int v = s * 4 + lg;
        w3v[s] = (v < WD) ? w3[v] : 0.0f;
    }

    __syncthreads();

    // ---- fill wfrag from LDS: 8 x ds_read_b128 per lane ----
    // A-row lr holds W2 row vrow = vt*16 + (lr&3)*4 + (lr>>2)
    bf16x8 wfrag[4][2];
    const int vsub = ((lr & 3) << 2) + (lr >> 2);
#pragma unroll
    for (int vt = 0; vt < 4; ++vt) {
        const int vrow = vt * 16 + vsub;
        const int base = vrow << 6;
        const int sw   = (vrow & 7) << 3;
#pragma unroll
        for (int kt = 0; kt < 2; ++kt) {
            const int off = base + ((((kt << 2) + lg) << 3) ^ sw);
            wfrag[vt][kt] = *reinterpret_cast<const bf16x8*>(&w2s[off]);
        }
    }

    float* __restrict__ dst = out + (size_t)m * BSZ;   // MODE 0 base
    const int b0 = ch * BCH + wid * (BCH / 4);         // wave's 256-row slice

#pragma unroll 1
    for (int it = 0; it < ITERS; ++it) {
        const int bb = b0 + it * 16;
        const float u = U[bb + lr];

        // layer 1 -> B fragments (batch col = lr); pad slots constant 0
        bf16x8 a0, a1 = {};
#pragma unroll
        for (int e = 0; e < 8; ++e)
            a0[e] = (__bf16)swishf(fmaf(u, w1v[e], b1v[e]));
#pragma unroll
        for (int e = 0; e < 5; ++e)
            a1[e] = (__bf16)swishf(fmaf(u, w1v[8 + e], b1v[8 + e]));

        // layer 2: D[v][batch]; b2 enters as C-in
        f32x4 acc[4];
#pragma unroll
        for (int vt = 0; vt < 4; ++vt) {
            acc[vt] = (f32x4){b2v[vt * 4 + 0], b2v[vt * 4 + 1],
                              b2v[vt * 4 + 2], b2v[vt * 4 + 3]};
            acc[vt] = __builtin_amdgcn_mfma_f32_16x16x32_bf16(wfrag[vt][0], a0, acc[vt], 0, 0, 0);
            acc[vt] = __builtin_amdgcn_mfma_f32_16x16x32_bf16(wfrag[vt][1], a1, acc[vt], 0, 0, 0);
        }

        // layer 3: 13 live slots, 4 chains, 2-step reduce over lg groups
        float pa = 0.0f, pb = 0.0f, pc = 0.0f, pd = 0.0f;
#pragma unroll
        for (int s = 0; s < 13; ++s) {
            const float y = swishf(acc[s >> 2][s & 3]);
            if ((s & 3) == 0)      pa = fmaf(w3v[s], y, pa);
            else if ((s & 3) == 1) pb = fmaf(w3v[s], y, pb);
            else if ((s & 3) == 2) pc = fmaf(w3v[s], y, pc);
            else                   pd = fmaf(w3v[s], y, pd);
        }
        float p = (pa + pb) + (pc + pd);
        p += __shfl_xor(p, 16);
        p += __shfl_xor(p, 32);

        if (lane < 16) {                    // lg==0: one result per batch col
            const int row = bb + lane;
            if (MODE == 0)      dst[row] = p + b3v;            // 64B/wave, coalesced
            else if (MODE == 1) out[((size_t)row * MT + m) * 2 + br] = p + b3v;
            else                out[(size_t)row * MT + m] = p + b3v;
        }
    }
}

// ws[NBR][256][4096] -> out. NBR=2: [b][m][re,im]; NBR=1: transpose to [b][m].
// (Verbatim from the round-2/5/6 PASS.)
template<int NBR>
__global__ __launch_bounds__(256) void rmat_interleave(
    const float* __restrict__ ws, float* __restrict__ out)
{
    __shared__ float tile[NBR][32][64 + 1];
    const int bt = blockIdx.x & 63;
    const int mt = blockIdx.x >> 6;
    const int b0 = bt * 64, m0 = mt * 32;

    for (int i = threadIdx.x; i < NBR * 32 * 64; i += 256) {
        const int brx = i >> 11;           // 0 when NBR==1
        const int r   = (i >> 6) & 31;
        const int c   = i & 63;
        tile[brx][r][c] = ws[(size_t)(brx * MT + m0 + r) * BSZ + b0 + c];
    }
    __syncthreads();

    const int tb   = threadIdx.x >> 2;
    const int part = threadIdx.x & 3;
    const int b = b0 + tb;
    if (NBR == 2) {
        float2* __restrict__ dstp =
            reinterpret_cast<float2*>(out) + (size_t)b * MT + m0 + part * 8;
#pragma unroll
        for (int k = 0; k < 8; ++k) {
            const int mm = part * 8 + k;
            dstp[k] = make_float2(tile[0][mm][tb], tile[1][mm][tb]);
        }
    } else {
        float* __restrict__ dstp = out + (size_t)b * MT + m0 + part * 8;
#pragma unroll
        for (int k = 0; k < 8; ++k)
            dstp[k] = tile[0][part * 8 + k][tb];
    }
}

extern "C" void kernel_launch(void* const* d_in, const int* in_sizes, int n_in,
                              void* d_out, int out_size, void* d_ws, size_t ws_size,
                              hipStream_t stream) {
    const float* U   = (const float*)d_in[0];
    const float* W1r = (const float*)d_in[1];
    const float* b1r = (const float*)d_in[2];
    const float* W2r = (const float*)d_in[3];
    const float* b2r = (const float*)d_in[4];
    const float* W3r = (const float*)d_in[5];
    const float* b3r = (const float*)d_in[6];
    const float* W1i = (const float*)d_in[7];
    const float* b1i = (const float*)d_in[8];
    const float* W2i = (const float*)d_in[9];
    const float* b2i = (const float*)d_in[10];
    const float* W3i = (const float*)d_in[11];
    const float* b3i = (const float*)d_in[12];
    float* out = (float*)d_out;
    float* ws  = (float*)d_ws;

    const dim3 grid(MT * NCH), block(256);
    const size_t plane = (size_t)MT * BSZ;   // floats per branch

    if (out_size >= (int)(2 * plane)) {
        // d_out = [B][M] of (re,im) float pairs
        if (ws_size >= 2 * plane * sizeof(float)) {
            rmat_mlp_mfma<0><<<grid, block, 0, stream>>>(U, W1r, b1r, W2r, b2r, W3r, b3r, ws, 0);
            rmat_mlp_mfma<0><<<grid, block, 0, stream>>>(U, W1i, b1i, W2i, b2i, W3i, b3i, ws + plane, 1);
            rmat_interleave<2><<<dim3(512), block, 0, stream>>>(ws, out);
        } else {
            rmat_mlp_mfma<1><<<grid, block, 0, stream>>>(U, W1r, b1r, W2r, b2r, W3r, b3r, out, 0);
            rmat_mlp_mfma<1><<<grid, block, 0, stream>>>(U, W1i, b1i, W2i, b2i, W3i, b3i, out, 1);
        }
    } else {
        // d_out holds B*M float32 -> real branch only (harness drops imag)
        if (ws_size >= plane * sizeof(float)) {
            rmat_mlp_mfma<0><<<grid, block, 0, stream>>>(U, W1r, b1r, W2r, b2r, W3r, b3r, ws, 0);
            rmat_interleave<1><<<dim3(512), block, 0, stream>>>(ws, out);
        } else {
            rmat_mlp_mfma<2><<<grid, block, 0, stream>>>(U, W1r, b1r, W2r, b2r, W3r, b3r, out, 0);
        }
    }
}